// Round 3
// baseline (109018.335 us; speedup 1.0000x reference)
//
#include <hip/hip_runtime.h>

#define TT    8192
#define HD    1024
#define NBLK  256       // compute blocks (one relay wave elected per XCD)
#define NTHR  384       // waves 0-3: producers; wave 4: projector; wave 5: relay
#define NBUF  4         // ring depth — safety proofs below
#define FLAG_SPIN 128   // bounded local-flag spin before MALL fallback

typedef int i32x4 __attribute__((ext_vector_type(4)));
typedef int i32x2 __attribute__((ext_vector_type(2)));

// ---- MALL-coherent accesses (sc0 sc1: bypass L1+L2, coherent chip-wide) ---
__device__ __forceinline__ void llc_load_pair(const unsigned* p, i32x4& a, i32x4& b) {
  asm volatile("global_load_dwordx4 %0, %2, off sc0 sc1\n\t"
               "global_load_dwordx4 %1, %3, off sc0 sc1\n\t"
               "s_waitcnt vmcnt(0)"
               : "=&v"(a), "=&v"(b)
               : "v"(p), "v"(p + 4)
               : "memory");
}
__device__ __forceinline__ void llc_store2(unsigned* p, unsigned lo, unsigned hi) {
  i32x2 v; v.x = (int)lo; v.y = (int)hi;
  asm volatile("global_store_dwordx2 %0, %1, off sc0 sc1"
               :: "v"(p), "v"(v) : "memory");
}

// ---- XCD-local (agent-scope) accesses (sc0: bypass L1, coherent at L2) ----
__device__ __forceinline__ unsigned l2_load1(const unsigned* p) {
  unsigned r;
  asm volatile("global_load_dword %0, %1, off sc0\n\ts_waitcnt vmcnt(0)"
               : "=v"(r) : "v"(p) : "memory");
  return r;
}
__device__ __forceinline__ void l2_store1(unsigned* p, unsigned v) {
  asm volatile("global_store_dword %0, %1, off sc0" :: "v"(p), "v"(v) : "memory");
}
__device__ __forceinline__ float4 l2_loadf4(const float* p) {
  i32x4 r;
  asm volatile("global_load_dwordx4 %0, %1, off sc0\n\ts_waitcnt vmcnt(0)"
               : "=v"(r) : "v"(p) : "memory");
  float4 f;
  f.x = __int_as_float(r.x); f.y = __int_as_float(r.y);
  f.z = __int_as_float(r.z); f.w = __int_as_float(r.w);
  return f;
}

__device__ __forceinline__ float sigf(float z) {
  return 1.0f / (1.0f + __expf(-z));
}
__device__ __forceinline__ float tanh_fast(float z) {
  float az = fabsf(z);
  float e  = __expf(2.0f * az);          // >= 1
  float t  = 1.0f - 2.0f / (e + 1.0f);
  return z < 0.0f ? -t : t;
}

__device__ __forceinline__ int read_xcc_id() {
  // HW_REG_XCC_ID = 20 (gfx940+); imm = id | (off<<6) | ((size-1)<<11)
  return __builtin_amdgcn_s_getreg(20 | (0 << 6) | (31 << 11)) & 7;
}

#define FMA4(acc, hvv, wvv)                                      \
  acc = fmaf((hvv).x, (wvv).x, acc);                             \
  acc = fmaf((hvv).y, (wvv).y, acc);                             \
  acc = fmaf((hvv).z, (wvv).z, acc);                             \
  acc = fmaf((hvv).w, (wvv).w, acc);

// ws layout (dwords):
//   ctr [8*16]      election counters, 64B apart
//   flag[8*64]      per-XCD flags, 256B apart      (sc0 domain)
//   hbuf[NBUF*HD*2] tagged pairs {val,tag}, MALL   (sc0 sc1 domain)
//   xbuf[8*NBUF*HD] republished values, per-XCD L2 (sc0 domain)
//
// hbuf: h of step t -> ring slot t%4, tag t+1 (8-B store: tag certifies val).
// ONLY the 8 relay waves poll hbuf (kills the round-2 MALL poll storm).
// Relay phase t: self-verify all 1024 pairs of h_{t-1}; write own h_lds;
// republish 4KB values to xbuf[xcd] slot (t-1)%4 (sc0); s_waitcnt vmcnt(0);
// store flag[xcd]=t (sc0).  vmcnt(0) between value and flag stores orders
// them at L2, so flag>=t certifies the slot for same-XCD readers.
//
// hbuf RING SAFETY: producer stores h_t only after consuming h_{t-1}, which
// required its XCD relay to publish h_{t-1}, which required the relay to see
// ALL h_{t-1} tags, which required every block to finish step t-1, hence to
// have completed (vmcnt(0)) every read of slot t%4 (last touched for h_{t-4}
// at step t-3).  NBUF=4 leaves 2 steps of slack.  QED.
// xbuf RING SAFETY: relay overwrites slot (t-1)%4 (killing h_{t-5}) only
// after all producers stored h_{t-1}, i.e. all blocks passed step t-1, i.e.
// completed their step t-4 one-shot reads of that slot.  QED.
//
// FALLBACK: consumers spin on the local flag at most FLAG_SPIN rounds, then
// self-verify directly at the MALL (round-2 path).  If the XCC grouping or
// sc0 L2-locality assumption is ever wrong this degrades to slow-but-correct
// instead of livelock.
extern "C" __global__ __launch_bounds__(NTHR, 1)
void lstm_persistent(const float* __restrict__ x,
                     const float* __restrict__ W_ih,
                     const float* __restrict__ W_hh,
                     const float* __restrict__ b_ih,
                     const float* __restrict__ b_hh,
                     const float* __restrict__ W_fc,
                     const float* __restrict__ b_fc,
                     float* __restrict__ out,
                     unsigned* __restrict__ ws)
{
  unsigned* ctr  = ws;                   // 8 x 16 dwords
  unsigned* flag = ws + 128;             // 8 x 64 dwords
  unsigned* hbuf = ws + 640;             // NBUF*HD*2 dwords (32 KB)
  float*    xbuf = (float*)(ws + 8832);  // 8*NBUF*HD floats (128 KB)

  const int tid = threadIdx.x;
  const int blk = blockIdx.x;

  __shared__ float x_lds[TT];        // 32 KB
  __shared__ float h_lds[2][HD];     //  8 KB double-buffered h broadcast
  __shared__ int   s_info[2];        // [0]=xcd, [1]=is_relay_block

  const int wave = tid >> 6;
  const int lane = tid & 63;
  const int g    = lane >> 4;        // gate 0..3 (i,f,g,o)
  const int kc   = lane & 15;
  const int unit = blk * 4 + wave;   // waves 0..3 only

  for (int i = tid; i < TT / 4; i += NTHR)
    ((float4*)x_lds)[i] = ((const float4*)x)[i];

  if (tid == 0) {
    int xcd = read_xcc_id();
    unsigned prev = atomicAdd(&ctr[xcd << 4], 1u);   // device-scope
    s_info[0] = xcd;
    s_info[1] = (prev == 0) ? 1 : 0;
  }

  float4 w4[16];
  float  wih_g[4], bs_g[4];
  float4 wfc4[4];
  float  bfc_val = 0.0f;

  if (wave < 4) {
    const float* wr = W_hh + (size_t)(g * HD + unit) * HD + kc * 4;
#pragma unroll
    for (int m = 0; m < 16; ++m)
      w4[m] = *((const float4*)(wr + m * 64));
#pragma unroll
    for (int q = 0; q < 4; ++q) {
      int r = q * HD + unit;
      wih_g[q] = W_ih[r];
      bs_g[q]  = b_ih[r] + b_hh[r];
    }
  } else if (wave == 4) {
#pragma unroll
    for (int m = 0; m < 4; ++m)
      wfc4[m] = *((const float4*)(W_fc + m * 256 + lane * 4));
    bfc_val = b_fc[0];
  }
  float c_state = 0.0f;
  __syncthreads();                   // x_lds + s_info ready

  const int  xcd    = s_info[0];
  const bool relayB = (s_info[1] != 0);
  unsigned*  flagp  = flag + (xcd << 6);
  float*     xb     = xbuf + (size_t)xcd * (NBUF * HD);

  // ---- the sequential scan ---------------------------------------------
  for (int t = 0; t < TT; ++t) {
    float accs = 0.0f;

    if (t > 0) {
      const int slot = (t - 1) & (NBUF - 1);

      if (relayB) {
        if (wave == 5) {
          // ---- relay: self-verify h_{t-1} at the MALL (8 pollers chip-wide)
          const unsigned want = (unsigned)t;
          const unsigned* pp = hbuf + (size_t)slot * HD * 2 + lane * 4;
          i32x4 P0, P1, P2, P3, P4, P5, P6, P7;
          for (;;) {
            asm volatile(
              "global_load_dwordx4 %0, %8, off sc0 sc1\n\t"
              "global_load_dwordx4 %1, %8, off offset:1024 sc0 sc1\n\t"
              "global_load_dwordx4 %2, %8, off offset:2048 sc0 sc1\n\t"
              "global_load_dwordx4 %3, %8, off offset:3072 sc0 sc1\n\t"
              "global_load_dwordx4 %4, %9, off sc0 sc1\n\t"
              "global_load_dwordx4 %5, %9, off offset:1024 sc0 sc1\n\t"
              "global_load_dwordx4 %6, %9, off offset:2048 sc0 sc1\n\t"
              "global_load_dwordx4 %7, %9, off offset:3072 sc0 sc1\n\t"
              "s_waitcnt vmcnt(0)"
              : "=&v"(P0), "=&v"(P1), "=&v"(P2), "=&v"(P3),
                "=&v"(P4), "=&v"(P5), "=&v"(P6), "=&v"(P7)
              : "v"(pp), "v"(pp + 1024)
              : "memory");
            bool ok = (P0.y == (int)want) && (P0.w == (int)want) &&
                      (P1.y == (int)want) && (P1.w == (int)want) &&
                      (P2.y == (int)want) && (P2.w == (int)want) &&
                      (P3.y == (int)want) && (P3.w == (int)want) &&
                      (P4.y == (int)want) && (P4.w == (int)want) &&
                      (P5.y == (int)want) && (P5.w == (int)want) &&
                      (P6.y == (int)want) && (P6.w == (int)want) &&
                      (P7.y == (int)want) && (P7.w == (int)want);
            if (__all(ok)) break;
          }
          // own-block LDS fill (value v = k*128 + lane*2)
          float* hl = &h_lds[t & 1][lane * 2];
#define LDSW(k, Pk) { float2 h2;                                   \
            h2.x = __int_as_float((Pk).x);                         \
            h2.y = __int_as_float((Pk).z);                         \
            *(float2*)(hl + (k) * 128) = h2; }
          LDSW(0, P0) LDSW(1, P1) LDSW(2, P2) LDSW(3, P3)
          LDSW(4, P4) LDSW(5, P5) LDSW(6, P6) LDSW(7, P7)
#undef LDSW
          // republish values to this XCD's L2 (sc0), then flag
          i32x2 V0, V1, V2, V3, V4, V5, V6, V7;
          V0.x = P0.x; V0.y = P0.z;  V1.x = P1.x; V1.y = P1.z;
          V2.x = P2.x; V2.y = P2.z;  V3.x = P3.x; V3.y = P3.z;
          V4.x = P4.x; V4.y = P4.z;  V5.x = P5.x; V5.y = P5.z;
          V6.x = P6.x; V6.y = P6.z;  V7.x = P7.x; V7.y = P7.z;
          float* vp = xb + (size_t)slot * HD + lane * 2;
          asm volatile(
            "global_store_dwordx2 %8, %0, off sc0\n\t"
            "global_store_dwordx2 %8, %1, off offset:512 sc0\n\t"
            "global_store_dwordx2 %8, %2, off offset:1024 sc0\n\t"
            "global_store_dwordx2 %8, %3, off offset:1536 sc0\n\t"
            "global_store_dwordx2 %8, %4, off offset:2048 sc0\n\t"
            "global_store_dwordx2 %8, %5, off offset:2560 sc0\n\t"
            "global_store_dwordx2 %8, %6, off offset:3072 sc0\n\t"
            "global_store_dwordx2 %8, %7, off offset:3584 sc0\n\t"
            "s_waitcnt vmcnt(0)"                 // values committed to L2 ...
            :: "v"(V0), "v"(V1), "v"(V2), "v"(V3),
               "v"(V4), "v"(V5), "v"(V6), "v"(V7), "v"(vp)
            : "memory");
          if (lane == 0) l2_store1(flagp, want); // ... before flag raises
        }
      } else if (tid < 256) {
        // ---- consumers: cheap local-flag poll, then one-shot L2 read ----
        unsigned f = 0;
        int spins = 0;
        do { f = l2_load1(flagp); } while (f < (unsigned)t && ++spins < FLAG_SPIN);
        float4 hv;
        if (f >= (unsigned)t) {
          hv = l2_loadf4(xb + (size_t)slot * HD + tid * 4);
        } else {
          // safety fallback: self-verified MALL read (slow, always correct)
          const unsigned* src = hbuf + ((size_t)slot * HD + tid * 4) * 2;
          const int want = t;
          i32x4 A, B;
          do {
            llc_load_pair(src, A, B);
          } while (!(A.y == want && A.w == want && B.y == want && B.w == want));
          hv.x = __int_as_float(A.x); hv.y = __int_as_float(A.z);
          hv.z = __int_as_float(B.x); hv.w = __int_as_float(B.z);
        }
        ((float4*)h_lds[t & 1])[tid] = hv;
      }
      __syncthreads();

      if (wave < 4) {
        const float* hp = h_lds[t & 1] + kc * 4;
        float s0 = 0.f, s1 = 0.f, s2 = 0.f, s3 = 0.f;
#pragma unroll
        for (int mb = 0; mb < 4; ++mb) {
          float4 ha = *((const float4*)(hp + (mb * 4 + 0) * 64));
          float4 hb = *((const float4*)(hp + (mb * 4 + 1) * 64));
          float4 hc = *((const float4*)(hp + (mb * 4 + 2) * 64));
          float4 hd = *((const float4*)(hp + (mb * 4 + 3) * 64));
          FMA4(s0, ha, w4[mb * 4 + 0]);
          FMA4(s1, hb, w4[mb * 4 + 1]);
          FMA4(s2, hc, w4[mb * 4 + 2]);
          FMA4(s3, hd, w4[mb * 4 + 3]);
        }
        accs = (s0 + s1) + (s2 + s3);
      } else if (wave == 4 && blk == ((t - 1) & 255)) {
        // fused output projection for step t-1 (dedicated wave, off path)
        float p = 0.f;
#pragma unroll
        for (int m = 0; m < 4; ++m) {
          float4 hm = *((const float4*)(h_lds[t & 1] + m * 256 + lane * 4));
          FMA4(p, hm, wfc4[m]);
        }
#pragma unroll
        for (int s = 1; s < 64; s <<= 1) p += __shfl_xor(p, s);
        if (lane == 0) out[t - 1] = p + bfc_val;
      }
    }

    if (wave < 4) {
#pragma unroll
      for (int s = 1; s < 16; s <<= 1)
        accs += __shfl_xor(accs, s);

      float gi = __shfl(accs, 0);
      float gf = __shfl(accs, 16);
      float gg = __shfl(accs, 32);
      float go = __shfl(accs, 48);

      if (lane == 0) {
        float xt = x_lds[t];
        gi += fmaf(xt, wih_g[0], bs_g[0]);
        gf += fmaf(xt, wih_g[1], bs_g[1]);
        gg += fmaf(xt, wih_g[2], bs_g[2]);
        go += fmaf(xt, wih_g[3], bs_g[3]);
        c_state  = sigf(gf) * c_state + sigf(gi) * tanh_fast(gg);
        float hn = sigf(go) * tanh_fast(c_state);
        llc_store2(hbuf + (((t & (NBUF - 1)) * HD + unit) * 2),
                   __float_as_uint(hn), (unsigned)(t + 1));  // fire & forget
      }
    }
  }

  // ---- epilogue: out[TT-1] by block 255 (tag-verified MALL read) --------
  if (blk == ((TT - 1) & 255)) {
    if (tid < 256) {
      const unsigned* src = hbuf + (((TT - 1) & (NBUF - 1)) * HD + tid * 4) * 2;
      i32x4 A, B;
      do {
        llc_load_pair(src, A, B);
      } while (!(A.y == TT && A.w == TT && B.y == TT && B.w == TT));
      float4 hv;
      hv.x = __int_as_float(A.x); hv.y = __int_as_float(A.z);
      hv.z = __int_as_float(B.x); hv.w = __int_as_float(B.z);
      ((float4*)h_lds[0])[tid] = hv;
    }
    __syncthreads();
    if (wave == 4) {
      float p = 0.f;
#pragma unroll
      for (int m = 0; m < 4; ++m) {
        float4 hm = *((const float4*)(h_lds[0] + m * 256 + lane * 4));
        FMA4(p, hm, wfc4[m]);
      }
#pragma unroll
      for (int s = 1; s < 64; s <<= 1) p += __shfl_xor(p, s);
      if (lane == 0) out[TT - 1] = p + bfc_val;
    }
  }
}

extern "C" void kernel_launch(void* const* d_in, const int* in_sizes, int n_in,
                              void* d_out, int out_size, void* d_ws, size_t ws_size,
                              hipStream_t stream) {
  const float* x   = (const float*)d_in[0];
  const float* Wih = (const float*)d_in[1];
  const float* Whh = (const float*)d_in[2];
  const float* bih = (const float*)d_in[3];
  const float* bhh = (const float*)d_in[4];
  const float* Wfc = (const float*)d_in[5];
  const float* bfc = (const float*)d_in[6];
  float* out = (float*)d_out;

  unsigned* ws = (unsigned*)d_ws;
  // zero ctr + flags + hbuf (tags); xbuf needs no init (flag certifies)
  size_t init_bytes = (size_t)(128 + 512 + NBUF * HD * 2) * sizeof(unsigned);
  hipMemsetAsync(d_ws, 0, init_bytes, stream);
  hipLaunchKernelGGL(lstm_persistent, dim3(NBLK), dim3(NTHR), 0, stream,
                     x, Wih, Whh, bih, bhh, Wfc, bfc, out, ws);
}

// Round 4
// 39257.639 us; speedup vs baseline: 2.7770x; 2.7770x over previous
//
#include <hip/hip_runtime.h>

#define TT    8192
#define HD    1024
#define NBLK  256       // compute blocks; no sequencer, no relay
#define NTHR  320       // waves 0-3: producers/consumers; wave 4: projector
#define NBUF  4         // value-ring depth — safety proof below

typedef int i32x4 __attribute__((ext_vector_type(4)));

// ---- MALL-coherent accesses (sc0 sc1: bypass L1+L2, coherent chip-wide) ---
__device__ __forceinline__ void llc_load4(const unsigned* p, i32x4& r) {
  asm volatile("global_load_dwordx4 %0, %1, off sc0 sc1\n\ts_waitcnt vmcnt(0)"
               : "=v"(r) : "v"(p) : "memory");
}
__device__ __forceinline__ float4 llc_loadf4(const float* p) {
  i32x4 r;
  asm volatile("global_load_dwordx4 %0, %1, off sc0 sc1\n\ts_waitcnt vmcnt(0)"
               : "=v"(r) : "v"(p) : "memory");
  float4 f;
  f.x = __int_as_float(r.x); f.y = __int_as_float(r.y);
  f.z = __int_as_float(r.z); f.w = __int_as_float(r.w);
  return f;
}
__device__ __forceinline__ void llc_store1(unsigned* p, unsigned v) {
  asm volatile("global_store_dword %0, %1, off sc0 sc1"
               :: "v"(p), "v"(v) : "memory");
}

__device__ __forceinline__ float sigf(float z) {
  return 1.0f / (1.0f + __expf(-z));
}
__device__ __forceinline__ float tanh_fast(float z) {
  float az = fabsf(z);
  float e  = __expf(2.0f * az);          // >= 1
  float t  = 1.0f - 2.0f / (e + 1.0f);
  return z < 0.0f ? -t : t;
}

#define FMA4(acc, hvv, wvv)                                      \
  acc = fmaf((hvv).x, (wvv).x, acc);                             \
  acc = fmaf((hvv).y, (wvv).y, acc);                             \
  acc = fmaf((hvv).z, (wvv).z, acc);                             \
  acc = fmaf((hvv).w, (wvv).w, acc);

// ws layout (dwords):
//   tags[NBLK]          1 KB: tags[b] = t+1  <=>  block b stored its 4 h_t
//   vals[NBUF*HD]      16 KB: untagged h ring, slot t%4
//
// CERTIFICATION: producer waves store values; __syncthreads() drains
// vmcnt(0) for every wave (compiler-emitted full waitcnt before s_barrier),
// so all 4 value stores are MALL-visible BEFORE tid0 issues the tag store.
// A consumer whose tag load returns >= t+1 was served AFTER the tag commit,
// hence after the value commits; its subsequent sc0 sc1 value read (issued
// later, served at the MALL, no stale cache path) must return them.
//
// RING SAFETY (NBUF=4): block B stores slot t%4 (killing h_{t-4}) at step t,
// strictly after B's step-(t-1) detect saw tags >= t-1 from EVERY block C,
// which C set only after finishing step t-2, hence after its step-(t-3)
// value reads of slot t%4 (h_{t-4}) completed with vmcnt(0).  Three steps
// of slack.  QED.
extern "C" __global__ __launch_bounds__(NTHR, 1)
void lstm_persistent(const float* __restrict__ x,
                     const float* __restrict__ W_ih,
                     const float* __restrict__ W_hh,
                     const float* __restrict__ b_ih,
                     const float* __restrict__ b_hh,
                     const float* __restrict__ W_fc,
                     const float* __restrict__ b_fc,
                     float* __restrict__ out,
                     unsigned* __restrict__ ws)
{
  unsigned* tags   = ws;               // NBLK dwords
  float*    vals   = (float*)(ws + NBLK);
  unsigned* vals_u = ws + NBLK;

  const int tid = threadIdx.x;
  const int blk = blockIdx.x;

  __shared__ float x_lds[TT];          // 32 KB: whole input sequence
  __shared__ float h_lds[2][HD];       //  8 KB: double-buffered h broadcast
  __shared__ unsigned go_sh;           // LDS release word (wave0 -> waves1-3)

  const int wave = tid >> 6;
  const int lane = tid & 63;
  const int g    = lane >> 4;          // gate 0..3 (i,f,g,o)
  const int kc   = lane & 15;          // k-chunk within the 1024-dot
  const int unit = blk * 4 + wave;     // waves 0..3 only

  // ---- one-time staging -------------------------------------------------
  for (int i = tid; i < TT / 4; i += NTHR)
    ((float4*)x_lds)[i] = ((const float4*)x)[i];
  if (tid == 0) go_sh = 0;

  float4 w4[16];
  float  wih_g[4], bs_g[4];
  float4 wfc4[4];
  float  bfc_val = 0.0f;

  if (wave < 4) {
    // W_hh row (gate g, unit) — lane covers k = m*64 + kc*4 + {0..3}
    const float* wr = W_hh + (size_t)(g * HD + unit) * HD + kc * 4;
#pragma unroll
    for (int m = 0; m < 16; ++m)
      w4[m] = *((const float4*)(wr + m * 64));
#pragma unroll
    for (int q = 0; q < 4; ++q) {
      int r = q * HD + unit;
      wih_g[q] = W_ih[r];
      bs_g[q]  = b_ih[r] + b_hh[r];
    }
  } else {
    // projector wave: W_fc fragment, lane covers h[m*256 + lane*4 + {0..3}]
#pragma unroll
    for (int m = 0; m < 4; ++m)
      wfc4[m] = *((const float4*)(W_fc + m * 256 + lane * 4));
    bfc_val = b_fc[0];
  }
  float c_state = 0.0f;
  __syncthreads();                     // x_lds + go_sh ready

  volatile unsigned* go_v = &go_sh;

  // ---- the sequential scan ---------------------------------------------
  for (int t = 0; t < TT; ++t) {
    float accs = 0.0f;

    if (t > 0) {
      const int slot = (t - 1) & (NBUF - 1);

      if (wave == 0) {
        // ---- detect: poll the 1 KB tag array (1 dwordx4 per lane) -------
        const unsigned* tp = tags + (lane << 2);
        const unsigned  tt = (unsigned)t;
        i32x4 T;
        do {
          llc_load4(tp, T);
        } while (!__all((unsigned)T.x >= tt && (unsigned)T.y >= tt &&
                        (unsigned)T.z >= tt && (unsigned)T.w >= tt));
        if (lane == 0) *go_v = tt;     // release siblings via LDS
      } else if (wave < 4) {
        while (*go_v < (unsigned)t) { }  // LDS spin, within-CU, ~60 cyc
      }
      // wave 4 falls through to the barrier directly

      if (tid < 256) {
        // certified one-shot value read (4 KB per block)
        float4 hv = llc_loadf4(vals + (size_t)slot * HD + tid * 4);
        ((float4*)h_lds[t & 1])[tid] = hv;
      }
      __syncthreads();

      if (wave < 4) {
        // fragments + 64 FMAs (4 independent sub-chains)
        const float* hp = h_lds[t & 1] + kc * 4;
        float s0 = 0.f, s1 = 0.f, s2 = 0.f, s3 = 0.f;
#pragma unroll
        for (int mb = 0; mb < 4; ++mb) {
          float4 ha = *((const float4*)(hp + (mb * 4 + 0) * 64));
          float4 hb = *((const float4*)(hp + (mb * 4 + 1) * 64));
          float4 hc = *((const float4*)(hp + (mb * 4 + 2) * 64));
          float4 hd = *((const float4*)(hp + (mb * 4 + 3) * 64));
          FMA4(s0, ha, w4[mb * 4 + 0]);
          FMA4(s1, hb, w4[mb * 4 + 1]);
          FMA4(s2, hc, w4[mb * 4 + 2]);
          FMA4(s3, hd, w4[mb * 4 + 3]);
        }
        accs = (s0 + s1) + (s2 + s3);
      } else if (blk == ((t - 1) & 255)) {
        // fused output projection for step t-1 (dedicated wave, off path)
        float p = 0.f;
#pragma unroll
        for (int m = 0; m < 4; ++m) {
          float4 hm = *((const float4*)(h_lds[t & 1] + m * 256 + lane * 4));
          FMA4(p, hm, wfc4[m]);
        }
#pragma unroll
        for (int s = 1; s < 64; s <<= 1) p += __shfl_xor(p, s);
        if (lane == 0) out[t - 1] = p + bfc_val;
      }
    }

    if (wave < 4) {
      // 4-round butterfly over kc: every lane in a gate-group gets the sum
#pragma unroll
      for (int s = 1; s < 16; s <<= 1)
        accs += __shfl_xor(accs, s);

      float gi = __shfl(accs, 0);
      float gf = __shfl(accs, 16);
      float gg = __shfl(accs, 32);
      float go = __shfl(accs, 48);

      if (lane == 0) {
        float xt = x_lds[t];
        gi += fmaf(xt, wih_g[0], bs_g[0]);
        gf += fmaf(xt, wih_g[1], bs_g[1]);
        gg += fmaf(xt, wih_g[2], bs_g[2]);
        go += fmaf(xt, wih_g[3], bs_g[3]);
        c_state  = sigf(gf) * c_state + sigf(gi) * tanh_fast(gg);
        float hn = sigf(go) * tanh_fast(c_state);
        llc_store1(vals_u + ((size_t)(t & (NBUF - 1)) * HD + unit),
                   __float_as_uint(hn));
      }
    }

    // __syncthreads drains vmcnt(0) for every wave -> all 4 value stores
    // are MALL-visible before the tag store below is issued.
    __syncthreads();
    if (tid == 0) llc_store1(tags + blk, (unsigned)(t + 1));
  }

  // ---- epilogue: out[TT-1] by block 255 ---------------------------------
  if (blk == ((TT - 1) & 255)) {
    const unsigned tt = (unsigned)TT;
    if (wave == 0) {
      const unsigned* tp = tags + (lane << 2);
      i32x4 T;
      do {
        llc_load4(tp, T);
      } while (!__all((unsigned)T.x >= tt && (unsigned)T.y >= tt &&
                      (unsigned)T.z >= tt && (unsigned)T.w >= tt));
      if (lane == 0) *go_v = tt;
    } else if (wave < 4) {
      while (*go_v < tt) { }
    }
    if (tid < 256) {
      float4 hv =
          llc_loadf4(vals + (size_t)((TT - 1) & (NBUF - 1)) * HD + tid * 4);
      ((float4*)h_lds[0])[tid] = hv;
    }
    __syncthreads();
    if (wave == 4) {
      float p = 0.f;
#pragma unroll
      for (int m = 0; m < 4; ++m) {
        float4 hm = *((const float4*)(h_lds[0] + m * 256 + lane * 4));
        FMA4(p, hm, wfc4[m]);
      }
#pragma unroll
      for (int s = 1; s < 64; s <<= 1) p += __shfl_xor(p, s);
      if (lane == 0) out[TT - 1] = p + bfc_val;
    }
  }
}

extern "C" void kernel_launch(void* const* d_in, const int* in_sizes, int n_in,
                              void* d_out, int out_size, void* d_ws, size_t ws_size,
                              hipStream_t stream) {
  const float* x   = (const float*)d_in[0];
  const float* Wih = (const float*)d_in[1];
  const float* Whh = (const float*)d_in[2];
  const float* bih = (const float*)d_in[3];
  const float* bhh = (const float*)d_in[4];
  const float* Wfc = (const float*)d_in[5];
  const float* bfc = (const float*)d_in[6];
  float* out = (float*)d_out;

  unsigned* ws = (unsigned*)d_ws;
  // zero tags (0 < any target); vals need no init (tag certifies)
  size_t init_bytes = (size_t)(NBLK + NBUF * HD) * sizeof(unsigned);
  hipMemsetAsync(d_ws, 0, init_bytes, stream);
  hipLaunchKernelGGL(lstm_persistent, dim3(NBLK), dim3(NTHR), 0, stream,
                     x, Wih, Whh, bih, bhh, Wfc, bfc, out, ws);
}

// Round 5
// 32521.439 us; speedup vs baseline: 3.3522x; 1.2071x over previous
//
#include <hip/hip_runtime.h>

#define TT    8192
#define HD    1024
#define NCB   64        // compute blocks; block NCB is the dedicated projector
#define NTHR  1024      // 16 waves; wave w owns unit blk*16+w
#define NBUF  16        // ring depth (provably safe; see proofs)
#define PLAG  12        // producers require ptag >= t - PLAG (3-step margin)

typedef int i32x2 __attribute__((ext_vector_type(2)));

// ---- MALL-coherent accesses (sc0 sc1: bypass L1+L2, coherent chip-wide) ---
__device__ __forceinline__ void llc_load2(const unsigned* p, unsigned& v, unsigned& tg) {
  i32x2 r;
  asm volatile("global_load_dwordx2 %0, %1, off sc0 sc1\n\ts_waitcnt vmcnt(0)"
               : "=v"(r) : "v"(p) : "memory");
  v = (unsigned)r.x; tg = (unsigned)r.y;
}
__device__ __forceinline__ unsigned llc_load1(const unsigned* p) {
  unsigned r;
  asm volatile("global_load_dword %0, %1, off sc0 sc1\n\ts_waitcnt vmcnt(0)"
               : "=v"(r) : "v"(p) : "memory");
  return r;
}
__device__ __forceinline__ void llc_store2(unsigned* p, unsigned lo, unsigned hi) {
  i32x2 v; v.x = (int)lo; v.y = (int)hi;
  asm volatile("global_store_dwordx2 %0, %1, off sc0 sc1"
               :: "v"(p), "v"(v) : "memory");
}
__device__ __forceinline__ void llc_store1(unsigned* p, unsigned v) {
  asm volatile("global_store_dword %0, %1, off sc0 sc1"
               :: "v"(p), "v"(v) : "memory");
}

__device__ __forceinline__ float sigf(float z) {
  return 1.0f / (1.0f + __expf(-z));
}
__device__ __forceinline__ float tanh_fast(float z) {
  float az = fabsf(z);
  float e  = __expf(2.0f * az);          // >= 1
  float t  = 1.0f - 2.0f / (e + 1.0f);
  return z < 0.0f ? -t : t;
}

#define FMA4(acc, hvv, wvv)                                      \
  acc = fmaf((hvv).x, (wvv).x, acc);                             \
  acc = fmaf((hvv).y, (wvv).y, acc);                             \
  acc = fmaf((hvv).z, (wvv).z, acc);                             \
  acc = fmaf((hvv).w, (wvv).w, acc);

// ws layout (dwords):
//   ptag[16]           one 64B line: projector progress (ptag = t  <=>
//                      projector consumed h_{t-1})
//   hbuf[NBUF*HD*2]    fused {value, tag} pairs, ring slot t%16, tag t+1
//
// PUBLICATION (minimal hops): producer lane0 stores {h, t+1} in ONE 8-B
// store, fire & forget.  Consumers SELF-VERIFY: each thread polls its one
// dwordx2 pair; the load that sees tag >= t already carries the value.
// One MALL round-trip on the critical path.
//
// CONTENTION: 65 blocks x 512 B/wave polls, perfectly coalesced; each 64-B
// line of the 8 KB slot is requested ~65x per round (vs 256+ in round 2,
// and vs a 16-line hot spot in round 4).
//
// PRODUCER RING SAFETY (NBUF=16): block B stores slot t%16 at step t
// (killing h_{t-16}) only after B's step-t poll saw ALL tags of h_{t-1},
// i.e. every block finished step t-1, hence completed (vmcnt(0)-terminated)
// its step-(t-15) poll reads of h_{t-16}.  14 steps of slack.  QED.
// PROJECTOR SAFETY: thread NTHR-1 of each compute block folds
// "ptag >= t - PLAG" into its poll; ptag >= t-12 means the projector
// consumed h_{t-13}, so h_{t-16} was consumed 3 steps before any
// overwrite.  No deadlock: projector waits only on producers' PAST stores
// (h_{tp-1}, tp <= t), producers wait only on projector's PAST progress;
// if producers stall at t with ptag < t-12, the projector's needed data
// (tags t-13..) is already published, so it advances.  QED.
extern "C" __global__ __launch_bounds__(NTHR, 1)
void lstm_persistent(const float* __restrict__ x,
                     const float* __restrict__ W_ih,
                     const float* __restrict__ W_hh,
                     const float* __restrict__ b_ih,
                     const float* __restrict__ b_hh,
                     const float* __restrict__ W_fc,
                     const float* __restrict__ b_fc,
                     float* __restrict__ out,
                     unsigned* __restrict__ ws)
{
  unsigned* ptag = ws;                 // 1 line
  unsigned* hbuf = ws + 16;            // NBUF*HD*2 dwords (128 KB)

  const int tid  = threadIdx.x;
  const int blk  = blockIdx.x;
  const int wave = tid >> 6;
  const int lane = tid & 63;

  __shared__ float x_lds[TT];          // 32 KB: whole input sequence
  __shared__ float h_lds[2][HD];       //  8 KB: double-buffered h broadcast
  __shared__ float red_lds[16];        // projector partial sums

  // ================= block NCB: dedicated output projector ===============
  if (blk == NCB) {
    const float wfc1 = W_fc[tid];      // (1,1024) row, coalesced
    const float bfc  = b_fc[0];
    for (int t = 1; t <= TT; ++t) {
      const unsigned want = (unsigned)t;
      const unsigned* src =
          hbuf + ((size_t)((t - 1) & (NBUF - 1)) * HD + tid) * 2;
      unsigned v, tg;
      do { llc_load2(src, v, tg); } while (tg < want);
      float p = __int_as_float(v) * wfc1;
#pragma unroll
      for (int s = 1; s < 64; s <<= 1) p += __shfl_xor(p, s);
      if (lane == 0) red_lds[wave] = p;
      __syncthreads();                 // all poll reads + partials done
      if (tid == 0) {
        float q = 0.f;
#pragma unroll
        for (int i = 0; i < 16; ++i) q += red_lds[i];
        out[t - 1] = q + bfc;
        llc_store1(ptag, want);        // certifies: consumed h_{t-1}
      }
      __syncthreads();                 // red_lds reusable next iteration
    }
    return;
  }

  // ================= blocks 0..63: compute ================================
  const int g    = lane >> 4;          // gate 0..3 (i,f,g,o)
  const int kc   = lane & 15;          // k-chunk within the 1024-dot
  const int unit = blk * 16 + wave;    // one unit per wave

  for (int i = tid; i < TT / 4; i += NTHR)
    ((float4*)x_lds)[i] = ((const float4*)x)[i];

  // W_hh row (gate g, unit) — lane covers k = m*64 + kc*4 + {0..3}
  float4 w4[16];
  {
    const float* wr = W_hh + (size_t)(g * HD + unit) * HD + kc * 4;
#pragma unroll
    for (int m = 0; m < 16; ++m)
      w4[m] = *((const float4*)(wr + m * 64));
  }
  float wih_g[4], bs_g[4];
#pragma unroll
  for (int q = 0; q < 4; ++q) {
    int r = q * HD + unit;
    wih_g[q] = W_ih[r];
    bs_g[q]  = b_ih[r] + b_hh[r];
  }
  float c_state = 0.0f;
  __syncthreads();                     // x_lds ready

  // ---- the sequential scan ----------------------------------------------
  for (int t = 0; t < TT; ++t) {
    float accs = 0.0f;

    if (t > 0) {
      // gather h_{t-1}: each thread self-verifies its ONE fused pair
      const unsigned want = (unsigned)t;
      const unsigned* src =
          hbuf + ((size_t)((t - 1) & (NBUF - 1)) * HD + tid) * 2;
      unsigned v, tg;
      if (tid == NTHR - 1) {
        // fold the projector-progress gate into this thread's poll
        bool ok;
        do {
          llc_load2(src, v, tg);
          unsigned pt = llc_load1(ptag);
          ok = (tg >= want) && ((int)pt >= t - PLAG);
        } while (!ok);
      } else {
        do { llc_load2(src, v, tg); } while (tg < want);
      }
      h_lds[t & 1][tid] = __int_as_float(v);
      __syncthreads();                 // h_{t-1} broadcast complete

      // fragments + 64 FMAs (4 independent sub-chains)
      const float* hp = h_lds[t & 1] + kc * 4;
      float s0 = 0.f, s1 = 0.f, s2 = 0.f, s3 = 0.f;
#pragma unroll
      for (int mb = 0; mb < 4; ++mb) {
        float4 ha = *((const float4*)(hp + (mb * 4 + 0) * 64));
        float4 hb = *((const float4*)(hp + (mb * 4 + 1) * 64));
        float4 hc = *((const float4*)(hp + (mb * 4 + 2) * 64));
        float4 hd = *((const float4*)(hp + (mb * 4 + 3) * 64));
        FMA4(s0, ha, w4[mb * 4 + 0]);
        FMA4(s1, hb, w4[mb * 4 + 1]);
        FMA4(s2, hc, w4[mb * 4 + 2]);
        FMA4(s3, hd, w4[mb * 4 + 3]);
      }
      accs = (s0 + s1) + (s2 + s3);
    }

    // 4-round butterfly over kc: every lane in a gate-group gets the sum
#pragma unroll
    for (int s = 1; s < 16; s <<= 1)
      accs += __shfl_xor(accs, s);

    float gi = __shfl(accs, 0);
    float gf = __shfl(accs, 16);
    float gg = __shfl(accs, 32);
    float go = __shfl(accs, 48);

    if (lane == 0) {
      float xt = x_lds[t];
      gi += fmaf(xt, wih_g[0], bs_g[0]);
      gf += fmaf(xt, wih_g[1], bs_g[1]);
      gg += fmaf(xt, wih_g[2], bs_g[2]);
      go += fmaf(xt, wih_g[3], bs_g[3]);
      c_state  = sigf(gf) * c_state + sigf(gi) * tanh_fast(gg);
      float hn = sigf(go) * tanh_fast(c_state);
      // fused {value, tag}: single 8-B fire-and-forget publication
      llc_store2(hbuf + ((size_t)(t & (NBUF - 1)) * HD + unit) * 2,
                 __float_as_uint(hn), (unsigned)(t + 1));
    }
  }
}

extern "C" void kernel_launch(void* const* d_in, const int* in_sizes, int n_in,
                              void* d_out, int out_size, void* d_ws, size_t ws_size,
                              hipStream_t stream) {
  const float* x   = (const float*)d_in[0];
  const float* Wih = (const float*)d_in[1];
  const float* Whh = (const float*)d_in[2];
  const float* bih = (const float*)d_in[3];
  const float* bhh = (const float*)d_in[4];
  const float* Wfc = (const float*)d_in[5];
  const float* bfc = (const float*)d_in[6];
  float* out = (float*)d_out;

  unsigned* ws = (unsigned*)d_ws;
  // zero ptag + all tags (0 < any wanted tag >= 1)
  size_t init_bytes = (size_t)(16 + NBUF * HD * 2) * sizeof(unsigned);
  hipMemsetAsync(d_ws, 0, init_bytes, stream);
  hipLaunchKernelGGL(lstm_persistent, dim3(NCB + 1), dim3(NTHR), 0, stream,
                     x, Wih, Whh, bih, bhh, Wfc, bfc, out, ws);
}